// Round 2
// baseline (113.827 us; speedup 1.0000x reference)
//
#include <hip/hip_runtime.h>

#define EPS 1e-7f

__device__ __forceinline__ float iou_log(float4 p, float4 g) {
    float hw1 = 0.5f * p.z, hh1 = 0.5f * p.w;
    float hw2 = 0.5f * g.z, hh2 = 0.5f * g.w;
    float iw = fmaxf(fminf(p.x + hw1, g.x + hw2) - fmaxf(p.x - hw1, g.x - hw2), 0.0f);
    float ih = fmaxf(fminf(p.y + hh1, g.y + hh2) - fmaxf(p.y - hh1, g.y - hh2), 0.0f);
    float inter = iw * ih;
    float uni = p.z * p.w + g.z * g.w - inter + EPS;
    float iou = inter / uni;
    iou = (iou == 0.0f) ? EPS : iou;   // jnp.where(iou==0, iou+eps, iou)
    return __logf(iou);
}

__global__ __launch_bounds__(256) void iou_fused_kernel(
    const float4* __restrict__ preds, const float4* __restrict__ gts,
    float* __restrict__ partial, unsigned int* __restrict__ counter,
    float* __restrict__ out, int n, float inv_n, int nblocks) {
    const int tid = blockIdx.x * blockDim.x + threadIdx.x;
    const int stride = gridDim.x * blockDim.x;

    float acc = 0.0f;
    int i = tid;
    // 4x unrolled main loop: 8 outstanding 16B loads per thread for MLP
    for (; i + 3 * stride < n; i += 4 * stride) {
        float4 p0 = preds[i];
        float4 p1 = preds[i + stride];
        float4 p2 = preds[i + 2 * stride];
        float4 p3 = preds[i + 3 * stride];
        float4 g0 = gts[i];
        float4 g1 = gts[i + stride];
        float4 g2 = gts[i + 2 * stride];
        float4 g3 = gts[i + 3 * stride];
        acc += iou_log(p0, g0);
        acc += iou_log(p1, g1);
        acc += iou_log(p2, g2);
        acc += iou_log(p3, g3);
    }
    for (; i < n; i += stride)
        acc += iou_log(preds[i], gts[i]);

    // 64-lane wave reduction
    #pragma unroll
    for (int off = 32; off > 0; off >>= 1)
        acc += __shfl_down(acc, off, 64);

    __shared__ float s[4];
    const int lane = threadIdx.x & 63;
    const int wv = threadIdx.x >> 6;
    if (lane == 0) s[wv] = acc;
    __syncthreads();

    // last-block-finishes: deterministic final reduce in double
    __shared__ bool last;
    if (threadIdx.x == 0) {
        partial[blockIdx.x] = s[0] + s[1] + s[2] + s[3];
        __threadfence();                       // release: partial visible device-wide
        unsigned int t = atomicAdd(counter, 1u);
        last = (t == (unsigned int)(nblocks - 1));
    }
    __syncthreads();
    if (!last) return;

    __threadfence();                           // acquire: see all partials
    double d = 0.0;
    for (int j = threadIdx.x; j < nblocks; j += blockDim.x)
        d += (double)partial[j];
    #pragma unroll
    for (int off = 32; off > 0; off >>= 1)
        d += __shfl_down(d, off, 64);
    __shared__ double sd[4];
    if (lane == 0) sd[wv] = d;
    __syncthreads();
    if (threadIdx.x == 0)
        out[0] = (float)(-(sd[0] + sd[1] + sd[2] + sd[3]) * (double)inv_n);
}

extern "C" void kernel_launch(void* const* d_in, const int* in_sizes, int n_in,
                              void* d_out, int out_size, void* d_ws, size_t ws_size,
                              hipStream_t stream) {
    const float4* preds = (const float4*)d_in[0];
    const float4* gts   = (const float4*)d_in[1];
    int n = in_sizes[0] / 4;           // number of boxes

    const int BLOCKS = 2048;
    const int THREADS = 256;

    float* partial = (float*)d_ws;
    unsigned int* counter = (unsigned int*)((char*)d_ws + BLOCKS * sizeof(float));
    float* out = (float*)d_out;

    hipMemsetAsync(counter, 0, sizeof(unsigned int), stream);
    iou_fused_kernel<<<BLOCKS, THREADS, 0, stream>>>(
        preds, gts, partial, counter, out, n, 1.0f / (float)n, BLOCKS);
}

// Round 3
// 47.229 us; speedup vs baseline: 2.4101x; 2.4101x over previous
//
#include <hip/hip_runtime.h>

#define EPS 1e-7f

__device__ __forceinline__ float iou_log(float4 p, float4 g) {
    float hw1 = 0.5f * p.z, hh1 = 0.5f * p.w;
    float hw2 = 0.5f * g.z, hh2 = 0.5f * g.w;
    float iw = fmaxf(fminf(p.x + hw1, g.x + hw2) - fmaxf(p.x - hw1, g.x - hw2), 0.0f);
    float ih = fmaxf(fminf(p.y + hh1, g.y + hh2) - fmaxf(p.y - hh1, g.y - hh2), 0.0f);
    float inter = iw * ih;
    float uni = p.z * p.w + g.z * g.w - inter + EPS;
    float iou = inter / uni;
    iou = (iou == 0.0f) ? EPS : iou;   // jnp.where(iou==0, iou+eps, iou)
    return __logf(iou);
}

__global__ __launch_bounds__(256) void iou_partial_kernel(
    const float4* __restrict__ preds, const float4* __restrict__ gts,
    float* __restrict__ partial, int n) {
    const int t = threadIdx.x;
    const int C = 1024;                        // float4s per block-window (4 per thread)
    const int step = gridDim.x * C;            // grid sweeps one contiguous window/iter
    const int nfull = (n / step) * step;

    float acc = 0.0f;
    for (int base = blockIdx.x * C; base < nfull; base += step) {
        // 8 contiguous-coalesced 16B loads in flight (128 B/thread/iter)
        float4 p0 = preds[base + t];
        float4 p1 = preds[base + t + 256];
        float4 p2 = preds[base + t + 512];
        float4 p3 = preds[base + t + 768];
        float4 g0 = gts[base + t];
        float4 g1 = gts[base + t + 256];
        float4 g2 = gts[base + t + 512];
        float4 g3 = gts[base + t + 768];
        acc += iou_log(p0, g0);
        acc += iou_log(p1, g1);
        acc += iou_log(p2, g2);
        acc += iou_log(p3, g3);
    }
    // tail (n not multiple of step): plain grid-stride
    for (int i = nfull + blockIdx.x * blockDim.x + t; i < n;
         i += gridDim.x * blockDim.x)
        acc += iou_log(preds[i], gts[i]);

    // 64-lane wave reduction
    #pragma unroll
    for (int off = 32; off > 0; off >>= 1)
        acc += __shfl_down(acc, off, 64);

    __shared__ float s[4];
    const int lane = threadIdx.x & 63;
    const int wv = threadIdx.x >> 6;
    if (lane == 0) s[wv] = acc;
    __syncthreads();
    if (threadIdx.x == 0)
        partial[blockIdx.x] = s[0] + s[1] + s[2] + s[3];
}

__global__ __launch_bounds__(256) void iou_final_kernel(
    const float* __restrict__ partial, int nb, float* __restrict__ out, float inv_n) {
    double acc = 0.0;
    for (int i = threadIdx.x; i < nb; i += blockDim.x)
        acc += (double)partial[i];

    #pragma unroll
    for (int off = 32; off > 0; off >>= 1)
        acc += __shfl_down(acc, off, 64);

    __shared__ double s[4];
    int lane = threadIdx.x & 63;
    int wv = threadIdx.x >> 6;
    if (lane == 0) s[wv] = acc;
    __syncthreads();
    if (threadIdx.x == 0) {
        double total = s[0] + s[1] + s[2] + s[3];
        out[0] = (float)(-total * (double)inv_n);
    }
}

extern "C" void kernel_launch(void* const* d_in, const int* in_sizes, int n_in,
                              void* d_out, int out_size, void* d_ws, size_t ws_size,
                              hipStream_t stream) {
    const float4* preds = (const float4*)d_in[0];
    const float4* gts   = (const float4*)d_in[1];
    int n = in_sizes[0] / 4;           // number of boxes

    float* partial = (float*)d_ws;
    float* out = (float*)d_out;

    const int BLOCKS = 2048;
    const int THREADS = 256;

    iou_partial_kernel<<<BLOCKS, THREADS, 0, stream>>>(preds, gts, partial, n);
    iou_final_kernel<<<1, THREADS, 0, stream>>>(partial, BLOCKS, out, 1.0f / (float)n);
}